// Round 9
// baseline (311.997 us; speedup 1.0000x reference)
//
#include <hip/hip_runtime.h>
#include <cmath>

#define BB 4
#define NN 4096
#define DD 244
#define DP 256
#define FSP 96
#define KC 3       // FSP/32 k-chunks for scores
#define MSPLIT 8   // m-chunks for max/spass
#define TPC 16     // tiles per chunk
#define NTRI 8256  // sum_{bx} (bx+1) tiles per batch

typedef _Float16 half8 __attribute__((ext_vector_type(8)));
typedef float float4v __attribute__((ext_vector_type(4)));
typedef unsigned int uint;

#define MFMA16 __builtin_amdgcn_mfma_f32_16x16x32_f16

static __device__ __forceinline__ uint pack2(float a, float b) {
    _Float16 ha = (_Float16)a, hb = (_Float16)b;
    unsigned short ua = __builtin_bit_cast(unsigned short, ha);
    unsigned short ub = __builtin_bit_cast(unsigned short, hb);
    return (uint)ua | ((uint)ub << 16);
}

// ---------------- prep: Wqt[c][k] = sum_j Wo[c][j] Wv[j][k]; uo = Wo @ bv ----------------
__global__ __launch_bounds__(256) void prep_wq(const float* __restrict__ Wv,
                                               const float* __restrict__ Wo,
                                               const float* __restrict__ bv,
                                               _Float16* __restrict__ Wqt,
                                               float* __restrict__ uo) {
    int k = blockIdx.x * 16 + (threadIdx.x & 15);
    int c = blockIdx.y * 16 + (threadIdx.x >> 4);
    float acc = 0.f;
    if (c < DD && k < DD)
        for (int j = 0; j < DD; ++j) acc += Wo[(size_t)c * DD + j] * Wv[(size_t)j * DD + k];
    Wqt[(size_t)c * DP + k] = (_Float16)acc;
    if (blockIdx.x == 0 && (threadIdx.x & 15) == 0) {
        float u = 0.f;
        if (c < DD)
            for (int kk = 0; kk < DD; ++kk) u += bv[kk] * Wo[(size_t)c * DD + kk];
        uo[c] = u;
    }
}

// feature order: k 0..63 = shell, 64 = charge, 65 = sqrt(mass), 66..95 = 0
__global__ __launch_bounds__(64) void prep_feat(const float* __restrict__ charge,
                                                const float* __restrict__ shell,
                                                const float* __restrict__ mass,
                                                _Float16* __restrict__ Qb,
                                                _Float16* __restrict__ Kb) {
    size_t row = blockIdx.x; int t = threadIdx.x;
    float v = shell[row * 64 + t];
    Kb[row * FSP + t] = (_Float16)v;
    Qb[row * FSP + t] = (_Float16)(-0.5f * v);
    int k2 = 64 + t;
    if (k2 < FSP) {
        float v2 = 0.f, q2 = 0.f;
        if (t == 0) { v2 = charge[row]; q2 = -1.0f * v2; }
        else if (t == 1) { v2 = sqrtf(mass[row]); q2 = -0.1f * v2; }
        Kb[row * FSP + k2] = (_Float16)v2;
        Qb[row * FSP + k2] = (_Float16)q2;
    }
}

// Uh [B*N][DP] f16 -> Ut [B][DP][N] f16
__global__ __launch_bounds__(256) void transpose_v(const _Float16* __restrict__ Vh,
                                                   _Float16* __restrict__ Vt) {
    __shared__ _Float16 tile[64][65];
    int n0 = blockIdx.x * 64, d0 = blockIdx.y * 64, b = blockIdx.z;
    int t = threadIdx.x;
#pragma unroll
    for (int i = 0; i < 16; ++i) {
        int idx = t + 256 * i;
        int r = idx >> 6, cc = idx & 63;
        tile[r][cc] = Vh[(size_t)(b * NN + n0 + r) * DP + d0 + cc];
    }
    __syncthreads();
#pragma unroll
    for (int i = 0; i < 16; ++i) {
        int idx = t + 256 * i;
        int dr = idx >> 6, nc = idx & 63;
        Vt[(size_t)b * DP * NN + (size_t)(d0 + dr) * NN + n0 + nc] = tile[nc][dr];
    }
}

// ---------------- 4-wave MFMA GEMM: C[r][c] = sum_k A[r][k]*W[c][k] + bias[c] ----------------
template <bool AF32, bool F16OUT>
__global__ __launch_bounds__(256) void gemm2(const void* __restrict__ A_,
                                             const _Float16* __restrict__ W,
                                             const float* __restrict__ bias,
                                             void* __restrict__ Cout) {
    int t = threadIdx.x;
    int w = t >> 6, l = t & 63, c = l & 15, g = l >> 4;
    int wr = w >> 1, wc = w & 1;
    int rowbase = blockIdx.x * 64 + wr * 32;
    int colbase = blockIdx.y * 128 + wc * 64;
    float4v acc[2][4];
#pragma unroll
    for (int i = 0; i < 2; ++i)
#pragma unroll
        for (int j = 0; j < 4; ++j) acc[i][j] = (float4v){0.f, 0.f, 0.f, 0.f};
#pragma unroll
    for (int kc = 0; kc < 8; ++kc) {
        int k0 = kc * 32 + g * 8;
        half8 af[2];
#pragma unroll
        for (int i = 0; i < 2; ++i) {
            int row = rowbase + 16 * i + c;
            if constexpr (AF32) {
                const float* ap = (const float*)A_ + (size_t)row * DD;
                float4 a0 = (k0 < DD) ? *(const float4*)(ap + k0) : make_float4(0, 0, 0, 0);
                float4 a1 = (k0 + 4 < DD) ? *(const float4*)(ap + k0 + 4) : make_float4(0, 0, 0, 0);
                af[i] = (half8){(_Float16)a0.x, (_Float16)a0.y, (_Float16)a0.z, (_Float16)a0.w,
                                (_Float16)a1.x, (_Float16)a1.y, (_Float16)a1.z, (_Float16)a1.w};
            } else {
                af[i] = *(const half8*)((const _Float16*)A_ + (size_t)row * DP + k0);
            }
        }
        half8 bf[4];
#pragma unroll
        for (int j = 0; j < 4; ++j)
            bf[j] = *(const half8*)(W + (size_t)(colbase + 16 * j + c) * DP + k0);
#pragma unroll
        for (int i = 0; i < 2; ++i)
#pragma unroll
            for (int j = 0; j < 4; ++j)
                acc[i][j] = MFMA16(af[i], bf[j], acc[i][j], 0, 0, 0);
    }
#pragma unroll
    for (int i = 0; i < 2; ++i)
#pragma unroll
        for (int j = 0; j < 4; ++j) {
            int col = colbase + 16 * j + c;
            float bcol = (col < DD) ? bias[col] : 0.f;
#pragma unroll
            for (int r = 0; r < 4; ++r) {
                int row = rowbase + 16 * i + 4 * g + r;
                float v = acc[i][j][r] + bcol;
                if constexpr (F16OUT) {
                    ((_Float16*)Cout)[(size_t)row * DP + col] = (_Float16)v;
                } else {
                    if (col < DD) ((float*)Cout)[(size_t)row * DD + col] = v;
                }
            }
        }
}

// ---------------- pass 1: exact row max, branch-free (MFMA + fmax only) ----------------
__global__ __launch_bounds__(64) void maxpass(const _Float16* __restrict__ Qb,
                                              const _Float16* __restrict__ Kb,
                                              float* __restrict__ partM) {
    int l = threadIdx.x, c = l & 15, g = l >> 4;
    int bx = blockIdx.x, chunk = blockIdx.y, b = blockIdx.z;
    size_t bN = (size_t)b * NN;
    int n0 = bx * 32;
    half8 qf[2][KC];
#pragma unroll
    for (int qg = 0; qg < 2; ++qg)
#pragma unroll
        for (int kc = 0; kc < KC; ++kc)
            qf[qg][kc] = *(const half8*)(Qb + (bN + n0 + 16 * qg + c) * FSP + kc * 32 + g * 8);
    int n[2] = {n0 + c, n0 + 16 + c};
    float M[2] = {-1e30f, -1e30f};
    int m_lo = chunk * TPC * 32;
#pragma unroll 2
    for (int t = 0; t < TPC; ++t) {
        int m0 = m_lo + t * 32;
        half8 kf[2][KC];
#pragma unroll
        for (int s = 0; s < 2; ++s)
#pragma unroll
            for (int kc = 0; kc < KC; ++kc)
                kf[s][kc] = *(const half8*)(Kb + (bN + m0 + 16 * s + c) * FSP + kc * 32 + g * 8);
#pragma unroll
        for (int qg = 0; qg < 2; ++qg)
#pragma unroll
            for (int s = 0; s < 2; ++s) {
                float4v p = (float4v){0.f, 0.f, 0.f, 0.f};
#pragma unroll
                for (int kc = 0; kc < KC; ++kc) p = MFMA16(kf[s][kc], qf[qg][kc], p, 0, 0, 0);
#pragma unroll
                for (int r = 0; r < 4; ++r) {
                    int m = m0 + 16 * s + 4 * g + r;
                    M[qg] = fmaxf(M[qg], p[r] - 0.3f * fabsf((float)(n[qg] - m)));
                }
            }
    }
#pragma unroll
    for (int qg = 0; qg < 2; ++qg) {
        M[qg] = fmaxf(M[qg], __shfl_xor(M[qg], 16));
        M[qg] = fmaxf(M[qg], __shfl_xor(M[qg], 32));
    }
    if (l < 32) {
        int qg = g;
        size_t bn = bN + n0 + 16 * qg + c;
        partM[(size_t)chunk * (BB * NN) + bn] = M[qg];
    }
}

__global__ __launch_bounds__(256) void mmerge(const float* __restrict__ partM,
                                              float* __restrict__ rowM) {
    size_t bn = (size_t)blockIdx.x * 256 + threadIdx.x;
    float M = -1e30f;
#pragma unroll
    for (int ch = 0; ch < MSPLIT; ++ch) M = fmaxf(M, partM[(size_t)ch * (BB * NN) + bn]);
    rowM[bn] = M;
}

// ---------------- pass 2: F,S + causal P write (exact M, no rescale branches) ----------------
// Pg layout per (b,bx): tiles 0..bx, slot = b*NTRI + bx(bx+1)/2 + tt, each tile
// 512 dwords: [qg 2][n' 16][m-dword 16] with the pv16 fragment order.
__global__ __launch_bounds__(64) void spass(const _Float16* __restrict__ Qb,
                                            const _Float16* __restrict__ Kb,
                                            const float* __restrict__ rowM,
                                            float* __restrict__ partFS,
                                            uint* __restrict__ Pg) {
    __shared__ __align__(16) uint Plds[2][16][20];
    int l = threadIdx.x, c = l & 15, g = l >> 4;
    int bx = blockIdx.x, chunk = blockIdx.y, b = blockIdx.z;
    size_t bN = (size_t)b * NN;
    int n0 = bx * 32;
    half8 qf[2][KC];
#pragma unroll
    for (int qg = 0; qg < 2; ++qg)
#pragma unroll
        for (int kc = 0; kc < KC; ++kc)
            qf[qg][kc] = *(const half8*)(Qb + (bN + n0 + 16 * qg + c) * FSP + kc * 32 + g * 8);
    int n[2] = {n0 + c, n0 + 16 + c};
    float Mq[2];
#pragma unroll
    for (int qg = 0; qg < 2; ++qg) Mq[qg] = rowM[bN + n0 + 16 * qg + c];
    float F[2] = {0.f, 0.f}, S[2] = {0.f, 0.f};
    size_t triB = ((size_t)b * NTRI + ((size_t)bx * (bx + 1)) / 2) * 512;
#pragma unroll 2
    for (int t = 0; t < TPC; ++t) {
        int tt = chunk * TPC + t;
        int m0 = tt * 32;
        half8 kf[2][KC];
#pragma unroll
        for (int s = 0; s < 2; ++s)
#pragma unroll
            for (int kc = 0; kc < KC; ++kc)
                kf[s][kc] = *(const half8*)(Kb + (bN + m0 + 16 * s + c) * FSP + kc * 32 + g * 8);
        bool causal = (tt <= bx);
#pragma unroll
        for (int qg = 0; qg < 2; ++qg) {
#pragma unroll
            for (int s = 0; s < 2; ++s) {
                float4v p = (float4v){0.f, 0.f, 0.f, 0.f};
#pragma unroll
                for (int kc = 0; kc < KC; ++kc) p = MFMA16(kf[s][kc], qf[qg][kc], p, 0, 0, 0);
                float wm[4];
#pragma unroll
                for (int r = 0; r < 4; ++r) {
                    int m = m0 + 16 * s + 4 * g + r;
                    float sc = p[r] - 0.3f * fabsf((float)(n[qg] - m));
                    float e = __expf(sc - Mq[qg]);
                    F[qg] += e;
                    wm[r] = (m <= n[qg]) ? e : 0.f;
                    S[qg] += wm[r];
                }
                if (causal) {
                    uint* dst = &Plds[qg][c][8 * s + 2 * g];
                    dst[0] = pack2(wm[0], wm[1]);
                    dst[1] = pack2(wm[2], wm[3]);
                }
            }
        }
        if (causal) {
            // per-wave LDS transpose -> coalesced global tile write
#pragma unroll
            for (int qg = 0; qg < 2; ++qg) {
                half8 pa = *(const half8*)&Plds[qg][c][4 * g];
                *(half8*)(Pg + triB + (size_t)tt * 512 + qg * 256 + c * 16 + 4 * g) = pa;
            }
        }
    }
#pragma unroll
    for (int qg = 0; qg < 2; ++qg) {
        F[qg] += __shfl_xor(F[qg], 16); F[qg] += __shfl_xor(F[qg], 32);
        S[qg] += __shfl_xor(S[qg], 16); S[qg] += __shfl_xor(S[qg], 32);
    }
    if (l < 32) {
        int qg = g;
        size_t bn = bN + n0 + 16 * qg + c;
        size_t idx = ((size_t)chunk * (BB * NN) + bn) * 2;
        partFS[idx + 0] = F[qg];
        partFS[idx + 1] = S[qg];
    }
}

__global__ __launch_bounds__(256) void amerge(const float* __restrict__ partFS,
                                              const float* __restrict__ valence,
                                              float* __restrict__ alphaB) {
    size_t bn = (size_t)blockIdx.x * 256 + threadIdx.x;
    float F = 0.f, S = 0.f;
#pragma unroll
    for (int ch = 0; ch < MSPLIT; ++ch) {
        size_t idx = ((size_t)ch * (BB * NN) + bn) * 2;
        F += partFS[idx + 0];
        S += partFS[idx + 1];
    }
    float val = valence[bn];
    float scale = fminf(val / (1.0f + 1e-6f), 1.0f);
    alphaB[bn] = scale / (scale * S + 1e-8f * F);
}

// out rows n >= 1024 get bo; pvg atomically accumulates alpha*acc on top
__global__ __launch_bounds__(256) void initout(const float* __restrict__ bo,
                                               float* __restrict__ out) {
    int n = 1024 + blockIdx.x, b = blockIdx.y, d = threadIdx.x;
    if (d < DD) out[((size_t)b * NN + n) * DD + d] = bo[d];
}

// ---------------- PV as pure GEMM from Pg (no exp/LDS/barriers) ----------------
__global__ __launch_bounds__(256) void pvg(const uint* __restrict__ Pg,
                                           const _Float16* __restrict__ Ut,
                                           const float* __restrict__ alphaB,
                                           const float* __restrict__ bo,
                                           float* __restrict__ out) {
    int t = threadIdx.x;
    int w = t >> 6, l = t & 63, c = l & 15, g = l >> 4;
    int gx = blockIdx.x, b = blockIdx.y;
    int bx, ch;
    if (gx < 32)       { bx = gx; ch = 0; }
    else if (gx < 96)  { int r = gx - 32;  bx = 32 + (r >> 1); ch = r & 1; }
    else if (gx < 192) { int r = gx - 96;  bx = 64 + r / 3;    ch = r % 3; }
    else               { int r = gx - 192; bx = 96 + (r >> 2); ch = r & 3; }
    int t0 = ch * 32;
    int t1 = min(t0 + 32, bx + 1);
    bool direct = (bx < 32);

    size_t bN = (size_t)b * NN;
    int n0 = bx * 32;
    float Aq[2];
#pragma unroll
    for (int qg = 0; qg < 2; ++qg) Aq[qg] = alphaB[bN + n0 + 16 * qg + c];
    float4v acc[2][4];
#pragma unroll
    for (int qg = 0; qg < 2; ++qg)
#pragma unroll
        for (int d = 0; d < 4; ++d) acc[qg][d] = (float4v){0.f, 0.f, 0.f, 0.f};
    const _Float16* UtB = Ut + (size_t)b * DP * NN;
    size_t triB = ((size_t)b * NTRI + ((size_t)bx * (bx + 1)) / 2) * 512;

#pragma unroll 2
    for (int tt = t0; tt < t1; ++tt) {
        const uint* pb = Pg + triB + (size_t)tt * 512 + c * 16 + 4 * g;
        half8 pa0 = *(const half8*)(pb);
        half8 pa1 = *(const half8*)(pb + 256);
        int m0p = tt * 32;
#pragma unroll
        for (int dcl = 0; dcl < 4; ++dcl) {
            int dc = 4 * w + dcl;
            half8 vf = *(const half8*)(UtB + (size_t)(dc * 16 + c) * NN + m0p + g * 8);
            acc[0][dcl] = MFMA16(pa0, vf, acc[0][dcl], 0, 0, 0);
            acc[1][dcl] = MFMA16(pa1, vf, acc[1][dcl], 0, 0, 0);
        }
    }
    if (direct) {
#pragma unroll
        for (int qg = 0; qg < 2; ++qg)
#pragma unroll
            for (int r = 0; r < 4; ++r) {
                float a = __shfl(Aq[qg], 4 * g + r);
                int nn = n0 + 16 * qg + 4 * g + r;
#pragma unroll
                for (int dcl = 0; dcl < 4; ++dcl) {
                    int col = (4 * w + dcl) * 16 + c;
                    if (col < DD)
                        out[(bN + nn) * DD + col] = a * acc[qg][dcl][r] + bo[col];
                }
            }
    } else {
#pragma unroll
        for (int qg = 0; qg < 2; ++qg)
#pragma unroll
            for (int r = 0; r < 4; ++r) {
                float a = __shfl(Aq[qg], 4 * g + r);
                int nn = n0 + 16 * qg + 4 * g + r;
#pragma unroll
                for (int dcl = 0; dcl < 4; ++dcl) {
                    int col = (4 * w + dcl) * 16 + c;
                    if (col < DD)
                        atomicAdd(&out[(bN + nn) * DD + col], a * acc[qg][dcl][r]);
                }
            }
    }
}

// ---------------- launch ----------------
extern "C" void kernel_launch(void* const* d_in, const int* in_sizes, int n_in,
                              void* d_out, int out_size, void* d_ws, size_t ws_size,
                              hipStream_t stream) {
    (void)in_sizes; (void)n_in; (void)out_size; (void)ws_size;
    const float* charge  = (const float*)d_in[0];
    const float* shell   = (const float*)d_in[1];
    const float* mass    = (const float*)d_in[2];
    const float* valence = (const float*)d_in[3];
    const float* x  = (const float*)d_in[5];
    const float* Wv = (const float*)d_in[6];
    const float* bv = (const float*)d_in[7];
    const float* Wo = (const float*)d_in[8];
    const float* bo = (const float*)d_in[9];
    float* out = (float*)d_out;

    const size_t BN = (size_t)BB * NN;
    char* w = (char*)d_ws;
    _Float16* Qb  = (_Float16*)w;   w += BN * FSP * 2;                 // 3.1 MB
    _Float16* Kb  = (_Float16*)w;   w += BN * FSP * 2;                 // 3.1 MB
    _Float16* Uh  = (_Float16*)w;   w += BN * DP * 2;                  // 8.4 MB
    _Float16* Ut  = (_Float16*)w;   w += BN * DP * 2;                  // 8.4 MB
    _Float16* Wqt = (_Float16*)w;   w += DP * DP * 2;                  // 128 KB
    float* uo     = (float*)w;      w += DP * 4;
    float* rowM   = (float*)w;      w += BN * 4;                       // 64 KB
    float* alphaB = (float*)w;      w += BN * 4;                       // 64 KB
    float* partM  = (float*)w;      w += (size_t)MSPLIT * BN * 4;      // 0.5 MB
    float* partFS = (float*)w;      w += (size_t)MSPLIT * BN * 2 * 4;  // 1.0 MB
    uint* Pg      = (uint*)w;       w += (size_t)BB * NTRI * 2048;     // 67.6 MB

    prep_wq<<<dim3(DP / 16, DP / 16), 256, 0, stream>>>(Wv, Wo, bv, Wqt, uo);
    prep_feat<<<BB * NN, 64, 0, stream>>>(charge, shell, mass, Qb, Kb);
    gemm2<true, true><<<dim3(BB * NN / 64, DP / 128), 256, 0, stream>>>(x, Wqt, uo, (void*)Uh);
    transpose_v<<<dim3(NN / 64, DP / 64, BB), 256, 0, stream>>>(Uh, Ut);
    maxpass<<<dim3(NN / 32, MSPLIT, BB), 64, 0, stream>>>(Qb, Kb, partM);
    mmerge<<<BN / 256, 256, 0, stream>>>(partM, rowM);
    spass<<<dim3(NN / 32, MSPLIT, BB), 64, 0, stream>>>(Qb, Kb, rowM, partFS, Pg);
    amerge<<<BN / 256, 256, 0, stream>>>(partFS, valence, alphaB);
    initout<<<dim3(NN - 1024, BB), 256, 0, stream>>>(bo, out);
    pvg<<<dim3(320, BB), 256, 0, stream>>>(Pg, Ut, alphaB, bo, out);
}

// Round 10
// 264.656 us; speedup vs baseline: 1.1789x; 1.1789x over previous
//
#include <hip/hip_runtime.h>
#include <cmath>

#define BB 4
#define NN 4096
#define DD 244
#define DP 256
#define KC 3       // k-chunks (96 features = 3 x 32)
#define MSPLIT 8   // m-chunks for max/spass
#define TPC 16     // tiles per chunk
#define NT 128     // 32-row tiles per batch
#define NTRI 8256  // sum_{bx} (bx+1) tiles per batch

typedef _Float16 half8 __attribute__((ext_vector_type(8)));
typedef float float4v __attribute__((ext_vector_type(4)));
typedef unsigned int uint;

#define MFMA16 __builtin_amdgcn_mfma_f32_16x16x32_f16

static __device__ __forceinline__ uint pack2(float a, float b) {
    _Float16 ha = (_Float16)a, hb = (_Float16)b;
    unsigned short ua = __builtin_bit_cast(unsigned short, ha);
    unsigned short ub = __builtin_bit_cast(unsigned short, hb);
    return (uint)ua | ((uint)ub << 16);
}

// fragment-layout helpers (halves):
//  QS/KS: ((((b*NT + tile)*2 + qg)*KC + kc)*64 + lane)*8
//  VB:    (((b*NT + tile)*16 + dc)*64 + lane)*8
static __device__ __forceinline__ size_t qk_off(int b, int tile, int qg, int kc, int l) {
    return ((((size_t)(b * NT + tile) * 2 + qg) * KC + kc) * 64 + l) * 8;
}
static __device__ __forceinline__ size_t vb_off(int b, int tile, int dc, int l) {
    return (((size_t)(b * NT + tile) * 16 + dc) * 64 + l) * 8;
}

// ---------------- prep: Wqt[c][k] = sum_j Wo[c][j] Wv[j][k]; uo = Wo @ bv ----------------
__global__ __launch_bounds__(256) void prep_wq(const float* __restrict__ Wv,
                                               const float* __restrict__ Wo,
                                               const float* __restrict__ bv,
                                               _Float16* __restrict__ Wqt,
                                               float* __restrict__ uo) {
    int k = blockIdx.x * 16 + (threadIdx.x & 15);
    int c = blockIdx.y * 16 + (threadIdx.x >> 4);
    float acc = 0.f;
    if (c < DD && k < DD)
        for (int j = 0; j < DD; ++j) acc += Wo[(size_t)c * DD + j] * Wv[(size_t)j * DD + k];
    Wqt[(size_t)c * DP + k] = (_Float16)acc;
    if (blockIdx.x == 0 && (threadIdx.x & 15) == 0) {
        float u = 0.f;
        if (c < DD)
            for (int kk = 0; kk < DD; ++kk) u += bv[kk] * Wo[(size_t)c * DD + kk];
        uo[c] = u;
    }
}

// ---------------- qk_pack: features -> fragment-contiguous QS/KS ----------------
// feature order: k 0..63 shell, 64 charge, 65 sqrt(mass), 66..95 zero.
// Q = -w*feat (w: shell 0.5, charge 1, mass 0.1) so score = dot(Q,K) - 0.3|n-m|.
__global__ __launch_bounds__(384) void qk_pack(const float* __restrict__ charge,
                                               const float* __restrict__ shell,
                                               const float* __restrict__ mass,
                                               _Float16* __restrict__ QS,
                                               _Float16* __restrict__ KS) {
    __shared__ float feat[32][96];
    int tile = blockIdx.x, b = blockIdx.y;
    size_t bN = (size_t)b * NN;
    int n0 = tile * 32;
    int t = threadIdx.x;
    for (int idx = t; idx < 32 * 64; idx += 384) {
        int r = idx >> 6, cc = idx & 63;
        feat[r][cc] = shell[(bN + n0 + r) * 64 + cc];
    }
    if (t < 32) {
        feat[t][64] = charge[bN + n0 + t];
        feat[t][65] = sqrtf(mass[bN + n0 + t]);
#pragma unroll
        for (int cc = 66; cc < 96; ++cc) feat[t][cc] = 0.f;
    }
    __syncthreads();
    int frag = t >> 6, l = t & 63;      // frag 0..5 = (qg, kc)
    int qg = frag / KC, kc = frag % KC;
    int row = 16 * qg + (l & 15);
    int kbase = kc * 32 + (l >> 4) * 8;
    half8 qv, kv;
#pragma unroll
    for (int j = 0; j < 8; ++j) {
        int k = kbase + j;
        float f = feat[row][k];
        float w = (k < 64) ? 0.5f : (k == 64 ? 1.0f : (k == 65 ? 0.1f : 0.f));
        kv[j] = (_Float16)f;
        qv[j] = (_Float16)(-w * f);
    }
    *(half8*)(QS + qk_off(b, tile, qg, kc, l)) = qv;
    *(half8*)(KS + qk_off(b, tile, qg, kc, l)) = kv;
}

// ---------------- 4-wave MFMA GEMM: C[r][c] = sum_k A[r][k]*W[c][k] + bias[c] ----------------
template <bool AF32, bool F16OUT>
__global__ __launch_bounds__(256) void gemm2(const void* __restrict__ A_,
                                             const _Float16* __restrict__ W,
                                             const float* __restrict__ bias,
                                             void* __restrict__ Cout) {
    int t = threadIdx.x;
    int w = t >> 6, l = t & 63, c = l & 15, g = l >> 4;
    int wr = w >> 1, wc = w & 1;
    int rowbase = blockIdx.x * 64 + wr * 32;
    int colbase = blockIdx.y * 128 + wc * 64;
    float4v acc[2][4];
#pragma unroll
    for (int i = 0; i < 2; ++i)
#pragma unroll
        for (int j = 0; j < 4; ++j) acc[i][j] = (float4v){0.f, 0.f, 0.f, 0.f};
#pragma unroll
    for (int kc = 0; kc < 8; ++kc) {
        int k0 = kc * 32 + g * 8;
        half8 af[2];
#pragma unroll
        for (int i = 0; i < 2; ++i) {
            int row = rowbase + 16 * i + c;
            if constexpr (AF32) {
                const float* ap = (const float*)A_ + (size_t)row * DD;
                float4 a0 = (k0 < DD) ? *(const float4*)(ap + k0) : make_float4(0, 0, 0, 0);
                float4 a1 = (k0 + 4 < DD) ? *(const float4*)(ap + k0 + 4) : make_float4(0, 0, 0, 0);
                af[i] = (half8){(_Float16)a0.x, (_Float16)a0.y, (_Float16)a0.z, (_Float16)a0.w,
                                (_Float16)a1.x, (_Float16)a1.y, (_Float16)a1.z, (_Float16)a1.w};
            } else {
                af[i] = *(const half8*)((const _Float16*)A_ + (size_t)row * DP + k0);
            }
        }
        half8 bf[4];
#pragma unroll
        for (int j = 0; j < 4; ++j)
            bf[j] = *(const half8*)(W + (size_t)(colbase + 16 * j + c) * DP + k0);
#pragma unroll
        for (int i = 0; i < 2; ++i)
#pragma unroll
            for (int j = 0; j < 4; ++j)
                acc[i][j] = MFMA16(af[i], bf[j], acc[i][j], 0, 0, 0);
    }
#pragma unroll
    for (int i = 0; i < 2; ++i)
#pragma unroll
        for (int j = 0; j < 4; ++j) {
            int col = colbase + 16 * j + c;
            float bcol = (col < DD) ? bias[col] : 0.f;
#pragma unroll
            for (int r = 0; r < 4; ++r) {
                int row = rowbase + 16 * i + 4 * g + r;
                float v = acc[i][j][r] + bcol;
                if constexpr (F16OUT) {
                    ((_Float16*)Cout)[(size_t)row * DP + col] = (_Float16)v;
                } else {
                    if (col < DD) ((float*)Cout)[(size_t)row * DD + col] = v;
                }
            }
        }
}

// ---------------- vb_pack: Uh [B*N][DP] -> fragment-contiguous VB ----------------
__global__ __launch_bounds__(256) void vb_pack(const _Float16* __restrict__ Uh,
                                               _Float16* __restrict__ VB) {
    __shared__ _Float16 ut[32][DP];
    int tile = blockIdx.x, b = blockIdx.y;
    size_t bN = (size_t)b * NN;
    int m0 = tile * 32;
    int t = threadIdx.x;
    for (int i = t; i < 32 * 32; i += 256) {
        int r = i >> 5, cs = (i & 31) * 8;
        *(half8*)&ut[r][cs] = *(const half8*)(Uh + (bN + m0 + r) * DP + cs);
    }
    __syncthreads();
    for (int u = t; u < 1024; u += 256) {
        int dc = u >> 6, l = u & 63, c = l & 15, g = l >> 4;
        half8 v;
#pragma unroll
        for (int j = 0; j < 8; ++j) v[j] = ut[g * 8 + j][dc * 16 + c];
        *(half8*)(VB + vb_off(b, tile, dc, l)) = v;
    }
}

// ---------------- pass 1: exact row max, branch-free ----------------
__global__ __launch_bounds__(64) void maxpass(const _Float16* __restrict__ QS,
                                              const _Float16* __restrict__ KS,
                                              float* __restrict__ partM) {
    int l = threadIdx.x, c = l & 15, g = l >> 4;
    int bx = blockIdx.x, chunk = blockIdx.y, b = blockIdx.z;
    size_t bN = (size_t)b * NN;
    int n0 = bx * 32;
    half8 qf[2][KC];
#pragma unroll
    for (int qg = 0; qg < 2; ++qg)
#pragma unroll
        for (int kc = 0; kc < KC; ++kc)
            qf[qg][kc] = *(const half8*)(QS + qk_off(b, bx, qg, kc, l));
    int n[2] = {n0 + c, n0 + 16 + c};
    float M[2] = {-1e30f, -1e30f};
#pragma unroll 2
    for (int t = 0; t < TPC; ++t) {
        int mt = chunk * TPC + t;
        int m0 = mt * 32;
        half8 kf[2][KC];
#pragma unroll
        for (int s = 0; s < 2; ++s)
#pragma unroll
            for (int kc = 0; kc < KC; ++kc)
                kf[s][kc] = *(const half8*)(KS + qk_off(b, mt, s, kc, l));
#pragma unroll
        for (int qg = 0; qg < 2; ++qg)
#pragma unroll
            for (int s = 0; s < 2; ++s) {
                float4v p = (float4v){0.f, 0.f, 0.f, 0.f};
#pragma unroll
                for (int kc = 0; kc < KC; ++kc) p = MFMA16(kf[s][kc], qf[qg][kc], p, 0, 0, 0);
#pragma unroll
                for (int r = 0; r < 4; ++r) {
                    int m = m0 + 16 * s + 4 * g + r;
                    M[qg] = fmaxf(M[qg], p[r] - 0.3f * fabsf((float)(n[qg] - m)));
                }
            }
    }
#pragma unroll
    for (int qg = 0; qg < 2; ++qg) {
        M[qg] = fmaxf(M[qg], __shfl_xor(M[qg], 16));
        M[qg] = fmaxf(M[qg], __shfl_xor(M[qg], 32));
    }
    if (l < 32) {
        int qg = g;
        size_t bn = bN + n0 + 16 * qg + c;
        partM[(size_t)chunk * (BB * NN) + bn] = M[qg];
    }
}

__global__ __launch_bounds__(256) void mmerge(const float* __restrict__ partM,
                                              float* __restrict__ rowM) {
    size_t bn = (size_t)blockIdx.x * 256 + threadIdx.x;
    float M = -1e30f;
#pragma unroll
    for (int ch = 0; ch < MSPLIT; ++ch) M = fmaxf(M, partM[(size_t)ch * (BB * NN) + bn]);
    rowM[bn] = M;
}

// ---------------- pass 2: F,S + causal P write (exact M, branch-free) ----------------
__global__ __launch_bounds__(64) void spass(const _Float16* __restrict__ QS,
                                            const _Float16* __restrict__ KS,
                                            const float* __restrict__ rowM,
                                            float* __restrict__ partFS,
                                            uint* __restrict__ Pg) {
    __shared__ __align__(16) uint Plds[2][16][20];
    int l = threadIdx.x, c = l & 15, g = l >> 4;
    int bx = blockIdx.x, chunk = blockIdx.y, b = blockIdx.z;
    size_t bN = (size_t)b * NN;
    int n0 = bx * 32;
    half8 qf[2][KC];
#pragma unroll
    for (int qg = 0; qg < 2; ++qg)
#pragma unroll
        for (int kc = 0; kc < KC; ++kc)
            qf[qg][kc] = *(const half8*)(QS + qk_off(b, bx, qg, kc, l));
    int n[2] = {n0 + c, n0 + 16 + c};
    float Mq[2];
#pragma unroll
    for (int qg = 0; qg < 2; ++qg) Mq[qg] = rowM[bN + n0 + 16 * qg + c];
    float F[2] = {0.f, 0.f}, S[2] = {0.f, 0.f};
    size_t triB = ((size_t)b * NTRI + ((size_t)bx * (bx + 1)) / 2) * 512;
#pragma unroll 2
    for (int t = 0; t < TPC; ++t) {
        int tt = chunk * TPC + t;
        int m0 = tt * 32;
        half8 kf[2][KC];
#pragma unroll
        for (int s = 0; s < 2; ++s)
#pragma unroll
            for (int kc = 0; kc < KC; ++kc)
                kf[s][kc] = *(const half8*)(KS + qk_off(b, tt, s, kc, l));
        bool causal = (tt <= bx);
#pragma unroll
        for (int qg = 0; qg < 2; ++qg) {
#pragma unroll
            for (int s = 0; s < 2; ++s) {
                float4v p = (float4v){0.f, 0.f, 0.f, 0.f};
#pragma unroll
                for (int kc = 0; kc < KC; ++kc) p = MFMA16(kf[s][kc], qf[qg][kc], p, 0, 0, 0);
                float wm[4];
#pragma unroll
                for (int r = 0; r < 4; ++r) {
                    int m = m0 + 16 * s + 4 * g + r;
                    float sc = p[r] - 0.3f * fabsf((float)(n[qg] - m));
                    float e = __expf(sc - Mq[qg]);
                    F[qg] += e;
                    wm[r] = (m <= n[qg]) ? e : 0.f;
                    S[qg] += wm[r];
                }
                if (causal) {
                    uint* dst = &Plds[qg][c][8 * s + 2 * g];
                    dst[0] = pack2(wm[0], wm[1]);
                    dst[1] = pack2(wm[2], wm[3]);
                }
            }
        }
        if (causal) {
#pragma unroll
            for (int qg = 0; qg < 2; ++qg) {
                half8 pa = *(const half8*)&Plds[qg][c][4 * g];
                *(half8*)(Pg + triB + (size_t)tt * 512 + qg * 256 + c * 16 + 4 * g) = pa;
            }
        }
    }
#pragma unroll
    for (int qg = 0; qg < 2; ++qg) {
        F[qg] += __shfl_xor(F[qg], 16); F[qg] += __shfl_xor(F[qg], 32);
        S[qg] += __shfl_xor(S[qg], 16); S[qg] += __shfl_xor(S[qg], 32);
    }
    if (l < 32) {
        int qg = g;
        size_t bn = bN + n0 + 16 * qg + c;
        size_t idx = ((size_t)chunk * (BB * NN) + bn) * 2;
        partFS[idx + 0] = F[qg];
        partFS[idx + 1] = S[qg];
    }
}

__global__ __launch_bounds__(256) void amerge(const float* __restrict__ partFS,
                                              const float* __restrict__ valence,
                                              float* __restrict__ alphaB) {
    size_t bn = (size_t)blockIdx.x * 256 + threadIdx.x;
    float F = 0.f, S = 0.f;
#pragma unroll
    for (int ch = 0; ch < MSPLIT; ++ch) {
        size_t idx = ((size_t)ch * (BB * NN) + bn) * 2;
        F += partFS[idx + 0];
        S += partFS[idx + 1];
    }
    float val = valence[bn];
    float scale = fminf(val / (1.0f + 1e-6f), 1.0f);
    alphaB[bn] = scale / (scale * S + 1e-8f * F);
}

__global__ __launch_bounds__(256) void initout(const float* __restrict__ bo,
                                               float* __restrict__ out) {
    int n = 1024 + blockIdx.x, b = blockIdx.y, d = threadIdx.x;
    if (d < DD) out[((size_t)b * NN + n) * DD + d] = bo[d];
}

// ---------------- PV as pure GEMM from Pg/VB ----------------
__global__ __launch_bounds__(256) void pvg(const uint* __restrict__ Pg,
                                           const _Float16* __restrict__ VB,
                                           const float* __restrict__ alphaB,
                                           const float* __restrict__ bo,
                                           float* __restrict__ out) {
    int t = threadIdx.x;
    int w = t >> 6, l = t & 63, c = l & 15, g = l >> 4;
    int gx = blockIdx.x, b = blockIdx.y;
    int bx, ch;
    if (gx < 32)       { bx = gx; ch = 0; }
    else if (gx < 96)  { int r = gx - 32;  bx = 32 + (r >> 1); ch = r & 1; }
    else if (gx < 192) { int r = gx - 96;  bx = 64 + r / 3;    ch = r % 3; }
    else               { int r = gx - 192; bx = 96 + (r >> 2); ch = r & 3; }
    int t0 = ch * 32;
    int t1 = min(t0 + 32, bx + 1);
    bool direct = (bx < 32);

    size_t bN = (size_t)b * NN;
    int n0 = bx * 32;
    float Aq[2];
#pragma unroll
    for (int qg = 0; qg < 2; ++qg) Aq[qg] = alphaB[bN + n0 + 16 * qg + c];
    float4v acc[2][4];
#pragma unroll
    for (int qg = 0; qg < 2; ++qg)
#pragma unroll
        for (int d = 0; d < 4; ++d) acc[qg][d] = (float4v){0.f, 0.f, 0.f, 0.f};
    size_t triB = ((size_t)b * NTRI + ((size_t)bx * (bx + 1)) / 2) * 512;

#pragma unroll 2
    for (int tt = t0; tt < t1; ++tt) {
        const uint* pb = Pg + triB + (size_t)tt * 512 + c * 16 + 4 * g;
        half8 pa0 = *(const half8*)(pb);
        half8 pa1 = *(const half8*)(pb + 256);
#pragma unroll
        for (int dcl = 0; dcl < 4; ++dcl) {
            int dc = 4 * w + dcl;
            half8 vf = *(const half8*)(VB + vb_off(b, tt, dc, l));
            acc[0][dcl] = MFMA16(pa0, vf, acc[0][dcl], 0, 0, 0);
            acc[1][dcl] = MFMA16(pa1, vf, acc[1][dcl], 0, 0, 0);
        }
    }
    if (direct) {
#pragma unroll
        for (int qg = 0; qg < 2; ++qg)
#pragma unroll
            for (int r = 0; r < 4; ++r) {
                float a = __shfl(Aq[qg], 4 * g + r);
                int nn = n0 + 16 * qg + 4 * g + r;
#pragma unroll
                for (int dcl = 0; dcl < 4; ++dcl) {
                    int col = (4 * w + dcl) * 16 + c;
                    if (col < DD)
                        out[(bN + nn) * DD + col] = a * acc[qg][dcl][r] + bo[col];
                }
            }
    } else {
#pragma unroll
        for (int qg = 0; qg < 2; ++qg)
#pragma unroll
            for (int r = 0; r < 4; ++r) {
                float a = __shfl(Aq[qg], 4 * g + r);
                int nn = n0 + 16 * qg + 4 * g + r;
#pragma unroll
                for (int dcl = 0; dcl < 4; ++dcl) {
                    int col = (4 * w + dcl) * 16 + c;
                    if (col < DD)
                        atomicAdd(&out[(bN + nn) * DD + col], a * acc[qg][dcl][r]);
                }
            }
    }
}

// ---------------- launch ----------------
extern "C" void kernel_launch(void* const* d_in, const int* in_sizes, int n_in,
                              void* d_out, int out_size, void* d_ws, size_t ws_size,
                              hipStream_t stream) {
    (void)in_sizes; (void)n_in; (void)out_size; (void)ws_size;
    const float* charge  = (const float*)d_in[0];
    const float* shell   = (const float*)d_in[1];
    const float* mass    = (const float*)d_in[2];
    const float* valence = (const float*)d_in[3];
    const float* x  = (const float*)d_in[5];
    const float* Wv = (const float*)d_in[6];
    const float* bv = (const float*)d_in[7];
    const float* Wo = (const float*)d_in[8];
    const float* bo = (const float*)d_in[9];
    float* out = (float*)d_out;

    const size_t BN = (size_t)BB * NN;
    char* w = (char*)d_ws;
    _Float16* QS  = (_Float16*)w;   w += BN * 96 * 2;                  // 3.1 MB
    _Float16* KS  = (_Float16*)w;   w += BN * 96 * 2;                  // 3.1 MB
    _Float16* Uh  = (_Float16*)w;   w += BN * DP * 2;                  // 8.4 MB
    _Float16* VB  = (_Float16*)w;   w += BN * DP * 2;                  // 8.4 MB
    _Float16* Wqt = (_Float16*)w;   w += DP * DP * 2;                  // 128 KB
    float* uo     = (float*)w;      w += DP * 4;
    float* rowM   = (float*)w;      w += BN * 4;                       // 64 KB
    float* alphaB = (float*)w;      w += BN * 4;                       // 64 KB
    float* partM  = (float*)w;      w += (size_t)MSPLIT * BN * 4;      // 0.5 MB
    float* partFS = (float*)w;      w += (size_t)MSPLIT * BN * 2 * 4;  // 1.0 MB
    uint* Pg      = (uint*)w;       w += (size_t)BB * NTRI * 2048;     // 67.6 MB

    prep_wq<<<dim3(DP / 16, DP / 16), 256, 0, stream>>>(Wv, Wo, bv, Wqt, uo);
    qk_pack<<<dim3(NT, BB), 384, 0, stream>>>(charge, shell, mass, QS, KS);
    gemm2<true, true><<<dim3(BB * NN / 64, DP / 128), 256, 0, stream>>>(x, Wqt, uo, (void*)Uh);
    vb_pack<<<dim3(NT, BB), 256, 0, stream>>>(Uh, VB);
    maxpass<<<dim3(NT, MSPLIT, BB), 64, 0, stream>>>(QS, KS, partM);
    mmerge<<<BN / 256, 256, 0, stream>>>(partM, rowM);
    spass<<<dim3(NT, MSPLIT, BB), 64, 0, stream>>>(QS, KS, rowM, partFS, Pg);
    amerge<<<BN / 256, 256, 0, stream>>>(partFS, valence, alphaB);
    initout<<<dim3(NN - 1024, BB), 256, 0, stream>>>(bo, out);
    pvg<<<dim3(320, BB), 256, 0, stream>>>(Pg, VB, alphaB, bo, out);
}

// Round 11
// 193.890 us; speedup vs baseline: 1.6091x; 1.3650x over previous
//
#include <hip/hip_runtime.h>
#include <cmath>

#define BB 4
#define NN 4096
#define DD 244
#define DP 256
#define KC 3       // k-chunks (96 features = 3 x 32)
#define NT 128     // 32-row tiles per batch
#define BAND 24    // band half-width in tiles (768 rows); exact: see analysis
#define NSLOT (BAND + 1)
#define MSPLIT 7   // chunks over the <=49-tile band (7 x 7)
#define CW 7       // tiles per chunk

typedef _Float16 half8 __attribute__((ext_vector_type(8)));
typedef float float4v __attribute__((ext_vector_type(4)));
typedef unsigned int uint;

#define MFMA16 __builtin_amdgcn_mfma_f32_16x16x32_f16

static __device__ __forceinline__ uint pack2(float a, float b) {
    _Float16 ha = (_Float16)a, hb = (_Float16)b;
    unsigned short ua = __builtin_bit_cast(unsigned short, ha);
    unsigned short ub = __builtin_bit_cast(unsigned short, hb);
    return (uint)ua | ((uint)ub << 16);
}

// fragment layouts: QS/KS ((((b*NT+tile)*2+qg)*KC+kc)*64+lane)*8
//                   VB    (((b*NT+tile)*16+dc)*64+lane)*8
static __device__ __forceinline__ size_t qk_off(int b, int tile, int qg, int kc, int l) {
    return ((((size_t)(b * NT + tile) * 2 + qg) * KC + kc) * 64 + l) * 8;
}
static __device__ __forceinline__ size_t vb_off(int b, int tile, int dc, int l) {
    return (((size_t)(b * NT + tile) * 16 + dc) * 64 + l) * 8;
}

// ---------------- prep: Wqt = Wo @ Wv (f16), uo = Wo @ bv ----------------
__global__ __launch_bounds__(256) void prep_wq(const float* __restrict__ Wv,
                                               const float* __restrict__ Wo,
                                               const float* __restrict__ bv,
                                               _Float16* __restrict__ Wqt,
                                               float* __restrict__ uo) {
    int k = blockIdx.x * 16 + (threadIdx.x & 15);
    int c = blockIdx.y * 16 + (threadIdx.x >> 4);
    float acc = 0.f;
    if (c < DD && k < DD)
        for (int j = 0; j < DD; ++j) acc += Wo[(size_t)c * DD + j] * Wv[(size_t)j * DD + k];
    Wqt[(size_t)c * DP + k] = (_Float16)acc;
    if (blockIdx.x == 0 && (threadIdx.x & 15) == 0) {
        float u = 0.f;
        if (c < DD)
            for (int kk = 0; kk < DD; ++kk) u += bv[kk] * Wo[(size_t)c * DD + kk];
        uo[c] = u;
    }
}

// ---------------- qk_pack: features -> fragment-contiguous QS/KS ----------------
__global__ __launch_bounds__(384) void qk_pack(const float* __restrict__ charge,
                                               const float* __restrict__ shell,
                                               const float* __restrict__ mass,
                                               _Float16* __restrict__ QS,
                                               _Float16* __restrict__ KS) {
    __shared__ float feat[32][96];
    int tile = blockIdx.x, b = blockIdx.y;
    size_t bN = (size_t)b * NN;
    int n0 = tile * 32;
    int t = threadIdx.x;
    for (int idx = t; idx < 32 * 64; idx += 384) {
        int r = idx >> 6, cc = idx & 63;
        feat[r][cc] = shell[(bN + n0 + r) * 64 + cc];
    }
    if (t < 32) {
        feat[t][64] = charge[bN + n0 + t];
        feat[t][65] = sqrtf(mass[bN + n0 + t]);
#pragma unroll
        for (int cc = 66; cc < 96; ++cc) feat[t][cc] = 0.f;
    }
    __syncthreads();
    int frag = t >> 6, l = t & 63;
    int qg = frag / KC, kc = frag % KC;
    int row = 16 * qg + (l & 15);
    int kbase = kc * 32 + (l >> 4) * 8;
    half8 qv, kv;
#pragma unroll
    for (int j = 0; j < 8; ++j) {
        int k = kbase + j;
        float f = feat[row][k];
        float w = (k < 64) ? 0.5f : (k == 64 ? 1.0f : (k == 65 ? 0.1f : 0.f));
        kv[j] = (_Float16)f;
        qv[j] = (_Float16)(-w * f);
    }
    *(half8*)(QS + qk_off(b, tile, qg, kc, l)) = qv;
    *(half8*)(KS + qk_off(b, tile, qg, kc, l)) = kv;
}

// ---------------- 4-wave MFMA GEMM (x @ Wqt^T + uo -> Uh f16) ----------------
template <bool AF32, bool F16OUT>
__global__ __launch_bounds__(256) void gemm2(const void* __restrict__ A_,
                                             const _Float16* __restrict__ W,
                                             const float* __restrict__ bias,
                                             void* __restrict__ Cout) {
    int t = threadIdx.x;
    int w = t >> 6, l = t & 63, c = l & 15, g = l >> 4;
    int wr = w >> 1, wc = w & 1;
    int rowbase = blockIdx.x * 64 + wr * 32;
    int colbase = blockIdx.y * 128 + wc * 64;
    float4v acc[2][4];
#pragma unroll
    for (int i = 0; i < 2; ++i)
#pragma unroll
        for (int j = 0; j < 4; ++j) acc[i][j] = (float4v){0.f, 0.f, 0.f, 0.f};
#pragma unroll
    for (int kc = 0; kc < 8; ++kc) {
        int k0 = kc * 32 + g * 8;
        half8 af[2];
#pragma unroll
        for (int i = 0; i < 2; ++i) {
            int row = rowbase + 16 * i + c;
            if constexpr (AF32) {
                const float* ap = (const float*)A_ + (size_t)row * DD;
                float4 a0 = (k0 < DD) ? *(const float4*)(ap + k0) : make_float4(0, 0, 0, 0);
                float4 a1 = (k0 + 4 < DD) ? *(const float4*)(ap + k0 + 4) : make_float4(0, 0, 0, 0);
                af[i] = (half8){(_Float16)a0.x, (_Float16)a0.y, (_Float16)a0.z, (_Float16)a0.w,
                                (_Float16)a1.x, (_Float16)a1.y, (_Float16)a1.z, (_Float16)a1.w};
            } else {
                af[i] = *(const half8*)((const _Float16*)A_ + (size_t)row * DP + k0);
            }
        }
        half8 bf[4];
#pragma unroll
        for (int j = 0; j < 4; ++j)
            bf[j] = *(const half8*)(W + (size_t)(colbase + 16 * j + c) * DP + k0);
#pragma unroll
        for (int i = 0; i < 2; ++i)
#pragma unroll
            for (int j = 0; j < 4; ++j)
                acc[i][j] = MFMA16(af[i], bf[j], acc[i][j], 0, 0, 0);
    }
#pragma unroll
    for (int i = 0; i < 2; ++i)
#pragma unroll
        for (int j = 0; j < 4; ++j) {
            int col = colbase + 16 * j + c;
            float bcol = (col < DD) ? bias[col] : 0.f;
#pragma unroll
            for (int r = 0; r < 4; ++r) {
                int row = rowbase + 16 * i + 4 * g + r;
                float v = acc[i][j][r] + bcol;
                if constexpr (F16OUT) {
                    ((_Float16*)Cout)[(size_t)row * DP + col] = (_Float16)v;
                } else {
                    if (col < DD) ((float*)Cout)[(size_t)row * DD + col] = v;
                }
            }
        }
}

// ---------------- vb_pack: Uh -> fragment-contiguous VB ----------------
__global__ __launch_bounds__(256) void vb_pack(const _Float16* __restrict__ Uh,
                                               _Float16* __restrict__ VB) {
    __shared__ _Float16 ut[32][DP];
    int tile = blockIdx.x, b = blockIdx.y;
    size_t bN = (size_t)b * NN;
    int m0 = tile * 32;
    int t = threadIdx.x;
    for (int i = t; i < 32 * 32; i += 256) {
        int r = i >> 5, cs = (i & 31) * 8;
        *(half8*)&ut[r][cs] = *(const half8*)(Uh + (bN + m0 + r) * DP + cs);
    }
    __syncthreads();
    for (int u = t; u < 1024; u += 256) {
        int dc = u >> 6, l = u & 63, c = l & 15, g = l >> 4;
        half8 v;
#pragma unroll
        for (int j = 0; j < 8; ++j) v[j] = ut[g * 8 + j][dc * 16 + c];
        *(half8*)(VB + vb_off(b, tile, dc, l)) = v;
    }
}

// ---------------- pass 1: banded exact row max ----------------
__global__ __launch_bounds__(64) void maxpass(const _Float16* __restrict__ QS,
                                              const _Float16* __restrict__ KS,
                                              float* __restrict__ partM) {
    int l = threadIdx.x, c = l & 15, g = l >> 4;
    int bx = blockIdx.x, chunk = blockIdx.y, b = blockIdx.z;
    size_t bN = (size_t)b * NN;
    int n0 = bx * 32;
    int lo = max(0, bx - BAND), hi = min(NT - 1, bx + BAND);
    int t0 = lo + chunk * CW, t1 = min(t0 + CW, hi + 1);
    half8 qf[2][KC];
#pragma unroll
    for (int qg = 0; qg < 2; ++qg)
#pragma unroll
        for (int kc = 0; kc < KC; ++kc)
            qf[qg][kc] = *(const half8*)(QS + qk_off(b, bx, qg, kc, l));
    int n[2] = {n0 + c, n0 + 16 + c};
    float M[2] = {-1e30f, -1e30f};
    for (int tt = t0; tt < t1; ++tt) {
        int m0 = tt * 32;
        half8 kf[2][KC];
#pragma unroll
        for (int s = 0; s < 2; ++s)
#pragma unroll
            for (int kc = 0; kc < KC; ++kc)
                kf[s][kc] = *(const half8*)(KS + qk_off(b, tt, s, kc, l));
#pragma unroll
        for (int qg = 0; qg < 2; ++qg)
#pragma unroll
            for (int s = 0; s < 2; ++s) {
                float4v p = (float4v){0.f, 0.f, 0.f, 0.f};
#pragma unroll
                for (int kc = 0; kc < KC; ++kc) p = MFMA16(kf[s][kc], qf[qg][kc], p, 0, 0, 0);
#pragma unroll
                for (int r = 0; r < 4; ++r) {
                    int m = m0 + 16 * s + 4 * g + r;
                    M[qg] = fmaxf(M[qg], p[r] - 0.3f * fabsf((float)(n[qg] - m)));
                }
            }
    }
#pragma unroll
    for (int qg = 0; qg < 2; ++qg) {
        M[qg] = fmaxf(M[qg], __shfl_xor(M[qg], 16));
        M[qg] = fmaxf(M[qg], __shfl_xor(M[qg], 32));
    }
    if (l < 32) {
        int qg = g;
        size_t bn = bN + n0 + 16 * qg + c;
        partM[(size_t)chunk * (BB * NN) + bn] = M[qg];
    }
}

__global__ __launch_bounds__(256) void mmerge(const float* __restrict__ partM,
                                              float* __restrict__ rowM) {
    size_t bn = (size_t)blockIdx.x * 256 + threadIdx.x;
    float M = -1e30f;
#pragma unroll
    for (int ch = 0; ch < MSPLIT; ++ch) M = fmaxf(M, partM[(size_t)ch * (BB * NN) + bn]);
    rowM[bn] = M;
}

// ---------------- pass 2: banded F,S + causal P tiles ----------------
// Pg slot j = tt - bx + BAND in [0, BAND]; per (b,bx): NSLOT tiles of 512 dw.
__global__ __launch_bounds__(64) void spass(const _Float16* __restrict__ QS,
                                            const _Float16* __restrict__ KS,
                                            const float* __restrict__ rowM,
                                            float* __restrict__ partFS,
                                            uint* __restrict__ Pg) {
    __shared__ __align__(16) uint Plds[2][16][20];
    int l = threadIdx.x, c = l & 15, g = l >> 4;
    int bx = blockIdx.x, chunk = blockIdx.y, b = blockIdx.z;
    size_t bN = (size_t)b * NN;
    int n0 = bx * 32;
    int lo = max(0, bx - BAND), hi = min(NT - 1, bx + BAND);
    int t0 = lo + chunk * CW, t1 = min(t0 + CW, hi + 1);
    half8 qf[2][KC];
#pragma unroll
    for (int qg = 0; qg < 2; ++qg)
#pragma unroll
        for (int kc = 0; kc < KC; ++kc)
            qf[qg][kc] = *(const half8*)(QS + qk_off(b, bx, qg, kc, l));
    int n[2] = {n0 + c, n0 + 16 + c};
    float Mq[2];
#pragma unroll
    for (int qg = 0; qg < 2; ++qg) Mq[qg] = rowM[bN + n0 + 16 * qg + c];
    float F[2] = {0.f, 0.f}, S[2] = {0.f, 0.f};
    size_t PgB = (size_t)(b * NT + bx) * NSLOT * 512;
    for (int tt = t0; tt < t1; ++tt) {
        int m0 = tt * 32;
        half8 kf[2][KC];
#pragma unroll
        for (int s = 0; s < 2; ++s)
#pragma unroll
            for (int kc = 0; kc < KC; ++kc)
                kf[s][kc] = *(const half8*)(KS + qk_off(b, tt, s, kc, l));
        bool causal = (tt <= bx);
#pragma unroll
        for (int qg = 0; qg < 2; ++qg) {
#pragma unroll
            for (int s = 0; s < 2; ++s) {
                float4v p = (float4v){0.f, 0.f, 0.f, 0.f};
#pragma unroll
                for (int kc = 0; kc < KC; ++kc) p = MFMA16(kf[s][kc], qf[qg][kc], p, 0, 0, 0);
                float wm[4];
#pragma unroll
                for (int r = 0; r < 4; ++r) {
                    int m = m0 + 16 * s + 4 * g + r;
                    float sc = p[r] - 0.3f * fabsf((float)(n[qg] - m));
                    float e = __expf(sc - Mq[qg]);
                    F[qg] += e;
                    wm[r] = (m <= n[qg]) ? e : 0.f;
                    S[qg] += wm[r];
                }
                if (causal) {
                    uint* dst = &Plds[qg][c][8 * s + 2 * g];
                    dst[0] = pack2(wm[0], wm[1]);
                    dst[1] = pack2(wm[2], wm[3]);
                }
            }
        }
        if (causal) {
            int j = tt - bx + BAND;
#pragma unroll
            for (int qg = 0; qg < 2; ++qg) {
                half8 pa = *(const half8*)&Plds[qg][c][4 * g];
                *(half8*)(Pg + PgB + (size_t)j * 512 + qg * 256 + c * 16 + 4 * g) = pa;
            }
        }
    }
#pragma unroll
    for (int qg = 0; qg < 2; ++qg) {
        F[qg] += __shfl_xor(F[qg], 16); F[qg] += __shfl_xor(F[qg], 32);
        S[qg] += __shfl_xor(S[qg], 16); S[qg] += __shfl_xor(S[qg], 32);
    }
    if (l < 32) {
        int qg = g;
        size_t bn = bN + n0 + 16 * qg + c;
        size_t idx = ((size_t)chunk * (BB * NN) + bn) * 2;
        partFS[idx + 0] = F[qg];
        partFS[idx + 1] = S[qg];
    }
}

__global__ __launch_bounds__(256) void amerge(const float* __restrict__ partFS,
                                              const float* __restrict__ valence,
                                              float* __restrict__ alphaB) {
    size_t bn = (size_t)blockIdx.x * 256 + threadIdx.x;
    float F = 0.f, S = 0.f;
#pragma unroll
    for (int ch = 0; ch < MSPLIT; ++ch) {
        size_t idx = ((size_t)ch * (BB * NN) + bn) * 2;
        F += partFS[idx + 0];
        S += partFS[idx + 1];
    }
    float val = valence[bn];
    float scale = fminf(val / (1.0f + 1e-6f), 1.0f);
    alphaB[bn] = scale / (scale * S + 1e-8f * F);
}

// ---------------- PV: banded pure GEMM, 8 waves (wave owns 2 d-columns), direct out ----------------
__global__ __launch_bounds__(512) void pvg(const uint* __restrict__ Pg,
                                           const _Float16* __restrict__ VB,
                                           const float* __restrict__ alphaB,
                                           const float* __restrict__ bo,
                                           float* __restrict__ out) {
    int t = threadIdx.x;
    int w = t >> 6, l = t & 63, c = l & 15, g = l >> 4;
    int bx = blockIdx.x, b = blockIdx.y;
    size_t bN = (size_t)b * NN;
    int n0 = bx * 32;
    int lo = max(0, bx - BAND);
    float Aq[2];
#pragma unroll
    for (int qg = 0; qg < 2; ++qg) Aq[qg] = alphaB[bN + n0 + 16 * qg + c];
    float4v acc[2][2];
#pragma unroll
    for (int qg = 0; qg < 2; ++qg)
#pragma unroll
        for (int d = 0; d < 2; ++d) acc[qg][d] = (float4v){0.f, 0.f, 0.f, 0.f};
    size_t PgB = (size_t)(b * NT + bx) * NSLOT * 512;

    for (int tt = lo; tt <= bx; ++tt) {
        int j = tt - bx + BAND;
        const uint* pb = Pg + PgB + (size_t)j * 512 + c * 16 + 4 * g;
        half8 pa0 = *(const half8*)(pb);
        half8 pa1 = *(const half8*)(pb + 256);
#pragma unroll
        for (int dcl = 0; dcl < 2; ++dcl) {
            int dc = 2 * w + dcl;
            half8 vf = *(const half8*)(VB + vb_off(b, tt, dc, l));
            acc[0][dcl] = MFMA16(pa0, vf, acc[0][dcl], 0, 0, 0);
            acc[1][dcl] = MFMA16(pa1, vf, acc[1][dcl], 0, 0, 0);
        }
    }
#pragma unroll
    for (int qg = 0; qg < 2; ++qg)
#pragma unroll
        for (int r = 0; r < 4; ++r) {
            float a = __shfl(Aq[qg], 4 * g + r);
            int nn = n0 + 16 * qg + 4 * g + r;
#pragma unroll
            for (int dcl = 0; dcl < 2; ++dcl) {
                int col = (2 * w + dcl) * 16 + c;
                if (col < DD)
                    out[(bN + nn) * DD + col] = a * acc[qg][dcl][r] + bo[col];
            }
        }
}

// ---------------- launch ----------------
extern "C" void kernel_launch(void* const* d_in, const int* in_sizes, int n_in,
                              void* d_out, int out_size, void* d_ws, size_t ws_size,
                              hipStream_t stream) {
    (void)in_sizes; (void)n_in; (void)out_size; (void)ws_size;
    const float* charge  = (const float*)d_in[0];
    const float* shell   = (const float*)d_in[1];
    const float* mass    = (const float*)d_in[2];
    const float* valence = (const float*)d_in[3];
    const float* x  = (const float*)d_in[5];
    const float* Wv = (const float*)d_in[6];
    const float* bv = (const float*)d_in[7];
    const float* Wo = (const float*)d_in[8];
    const float* bo = (const float*)d_in[9];
    float* out = (float*)d_out;

    const size_t BN = (size_t)BB * NN;
    char* w = (char*)d_ws;
    _Float16* QS  = (_Float16*)w;   w += BN * 96 * 2;                  // 3.1 MB
    _Float16* KS  = (_Float16*)w;   w += BN * 96 * 2;                  // 3.1 MB
    _Float16* Uh  = (_Float16*)w;   w += BN * DP * 2;                  // 8.4 MB
    _Float16* VB  = (_Float16*)w;   w += BN * DP * 2;                  // 8.4 MB
    _Float16* Wqt = (_Float16*)w;   w += DP * DP * 2;                  // 128 KB
    float* uo     = (float*)w;      w += DP * 4;
    float* rowM   = (float*)w;      w += BN * 4;                       // 64 KB
    float* alphaB = (float*)w;      w += BN * 4;                       // 64 KB
    float* partM  = (float*)w;      w += (size_t)MSPLIT * BN * 4;      // 0.5 MB
    float* partFS = (float*)w;      w += (size_t)MSPLIT * BN * 2 * 4;  // 0.9 MB
    uint* Pg      = (uint*)w;       w += (size_t)BB * NT * NSLOT * 2048; // 26.2 MB

    prep_wq<<<dim3(DP / 16, DP / 16), 256, 0, stream>>>(Wv, Wo, bv, Wqt, uo);
    qk_pack<<<dim3(NT, BB), 384, 0, stream>>>(charge, shell, mass, QS, KS);
    gemm2<true, true><<<dim3(BB * NN / 64, DP / 128), 256, 0, stream>>>(x, Wqt, uo, (void*)Uh);
    vb_pack<<<dim3(NT, BB), 256, 0, stream>>>(Uh, VB);
    maxpass<<<dim3(NT, MSPLIT, BB), 64, 0, stream>>>(QS, KS, partM);
    mmerge<<<BN / 256, 256, 0, stream>>>(partM, rowM);
    spass<<<dim3(NT, MSPLIT, BB), 64, 0, stream>>>(QS, KS, rowM, partFS, Pg);
    amerge<<<BN / 256, 256, 0, stream>>>(partFS, valence, alphaB);
    pvg<<<dim3(NT, BB), 512, 0, stream>>>(Pg, VB, alphaB, bo, out);
}